// Round 22
// baseline (81.128 us; speedup 1.0000x reference)
//
#include <hip/hip_runtime.h>
#include <stdint.h>

namespace {

constexpr int   B_   = 64;
constexpr int   F0_  = 1876;
constexpr int   F1_  = 1024;
constexpr int   F2_  = 10;
constexpr int   NT_  = 151;
constexpr int   NB1_ = 51;        // bins 0..50
constexpr float DT_  = 0.02f;
constexpr float SCL_  = 1073741824.0f;      // 2^30 fixed-point scale
constexpr float ISCL_ = 1.0f / 1073741824.0f;

constexpr int NBLK_T = 480;       // 30 i-tiles x 16 j-tiles

// workspace layout (bytes)
constexpr size_t OFF_W1T  = 0;                    // 1876*1024*4 = 7,684,096
constexpr size_t OFF_PAIR = 7684096;              // 64*1876*8   =   960,512
constexpr size_t OFF_BST  = OFF_PAIR + 960512;    // 64*52*4     =    13,312
constexpr size_t OFF_IDX1 = OFF_BST + 13312;      // 64*1024 u8  =    65,536

// ---------------------------------------------------------------------------
// k_prep: (a) blocks < 480: W1[j][i] f32 -> W1T[i][j] f32 (row stride 4096 B)
//         (b) blocks >= 480: per-b deterministic stable counting sort of ti
//             by bin k = clamp(ceil(ti*50),0,50).  Emits
//             sPair[b][pos] = { i*4096 (row byte offset), ti_bits } and
//             bstG[b][k] = bin start positions (52 entries, bst[51]=1876).
// ---------------------------------------------------------------------------
__global__ __launch_bounds__(256) void k_prep(const float* __restrict__ W1,
                                              const float* __restrict__ ti,
                                              float* __restrict__ W1T,
                                              uint2* __restrict__ sPair,
                                              uint32_t* __restrict__ bstG) {
  __shared__ uint32_t smem[13120];   // max(transpose tile, sort hist+bstart)
  const int t = threadIdx.x;
  if (blockIdx.x < NBLK_T) {
    float (*tile)[65] = (float (*)[65])smem;     // 64*65*4 = 16,640 <= 52,480
    const int bx = blockIdx.x;
    const int i0 = (bx % 30) * 64;     // 0..1856
    const int j0 = (bx / 30) * 64;
    const int c = t & 63, r4 = t >> 6;
    for (int jj = r4; jj < 64; jj += 4) {
      int i = i0 + c;
      tile[c][jj] = (i < F0_) ? W1[(size_t)(j0 + jj) * F0_ + i] : 0.0f;
    }
    __syncthreads();
    for (int ii = r4; ii < 64; ii += 4) {
      int i = i0 + ii;
      if (i < F0_) W1T[(size_t)i * F1_ + j0 + c] = tile[ii][c];
    }
  } else {
    uint32_t (*hist)[NB1_] = (uint32_t (*)[NB1_])smem;   // [256][51]
    uint32_t* bstart = smem + 256 * NB1_;                // [52]
    const int b = blockIdx.x - NBLK_T;
    for (int k = 0; k < NB1_; ++k) hist[t][k] = 0;
    __syncthreads();

    const float* tib = ti + (size_t)b * F0_;
    const int n0 = t * 8, n1 = (n0 + 8 < F0_) ? n0 + 8 : F0_;
    for (int n = n0; n < n1; ++n) {
      int k = (int)fminf(ceilf(tib[n] * 50.0f), 50.0f);  // ti >= 0 -> k >= 0
      hist[t][k]++;
    }
    __syncthreads();

    if (t < NB1_) {                  // exclusive prefix over 256 chunks
      uint32_t run = 0;
      for (int c = 0; c < 256; ++c) { uint32_t x = hist[c][t]; hist[c][t] = run; run += x; }
      bstart[t + 1] = run;           // bin totals
    }
    __syncthreads();
    if (t == 0) {                    // bin-start prefix; bstart[51] = 1876
      bstart[0] = 0;
      uint32_t acc = 0;
      for (int k = 0; k < NB1_; ++k) { uint32_t c = bstart[k + 1]; bstart[k + 1] = acc + c; acc += c; }
    }
    __syncthreads();

    uint2* out = sPair + (size_t)b * F0_;
    for (int n = n0; n < n1; ++n) {  // stable scatter
      float v = tib[n];
      int k = (int)fminf(ceilf(v * 50.0f), 50.0f);
      uint32_t pos = bstart[k] + hist[t][k]++;
      out[pos] = make_uint2((uint32_t)n << 12, __float_as_uint(v));  // i*4096
    }
    if (t <= NB1_) bstG[(size_t)b * (NB1_ + 1) + t] = bstart[t];
  }
}

// ---------------------------------------------------------------------------
// Layer 1 — sorted-run register accumulation, lane = j (combines the r5 sort
// with the r15+ conflict-free layout; eliminates the 7.4-cyc/op per-ELEMENT
// atomic wall measured in r16-r21 by flushing only at bin boundaries):
// 1024 blocks = b*16 + jg (XCD = jg%8, ~1 MB W slice L2-fit), 512 thr =
// 8 waves; wave wv owns sorted elements [e0,e1) (~235).  Per element: one
// broadcast ds_read_b64 (uniform addr) for {row_off, tv}, one COALESCED
// 256 B wave-load W1T[row][jg*64+lane], 2 VALU f32 accumulation in sorted
// (deterministic) order.  Bin boundaries from bstart -> inner loop is
// branch-free; flush = 2 int atomics per (wave,bin) (~8/wave total,
// quantized rn(x*2^30): <= 9 quantizations/bin ~ 4e-9, absmax-0.0 class).
// int adds commute -> bit-deterministic.  Phase 2: r19 verbatim.
// LDS 41.3 KB -> 3 blocks/CU = 24 waves/CU.
// ---------------------------------------------------------------------------
__global__ __launch_bounds__(512, 6) void k_main1(const uint2* __restrict__ sPair,
                                                  const uint32_t* __restrict__ bstG,
                                                  const float* __restrict__ W1T,
                                                  uint8_t* __restrict__ idx1) {
  __shared__ uint2    recs[F0_];       // 15,008 B
  __shared__ int      bins[2][NB1_][64];  // 26,112 B
  __shared__ uint32_t bst[NB1_ + 1];   //     208 B
  const int blk  = blockIdx.x;         // 1024
  const int b    = blk >> 4;
  const int jg   = blk & 15;
  const int tid  = threadIdx.x;
  const int lane = tid & 63;
  const int wv   = __builtin_amdgcn_readfirstlane(tid >> 6);  // 0..7

  {
    const uint4* src = (const uint4*)(sPair + (size_t)b * F0_);
    uint4* dst = (uint4*)recs;
    for (int s = tid; s < F0_ / 2; s += 512) dst[s] = src[s];   // 938 uint4
    if (tid <= NB1_) bst[tid] = bstG[(size_t)b * (NB1_ + 1) + tid];
    int4* p = (int4*)(&bins[0][0][0]);
    for (int s = tid; s < (2 * NB1_ * 64) / 4; s += 512) p[s] = make_int4(0, 0, 0, 0);
  }
  __syncthreads();

  // wave element-range: 1876 = 8*234 + 4
  const int cnt = 234 + (wv < 4 ? 1 : 0);
  const int e0  = wv * 234 + (wv < 4 ? wv : 4);
  const int e1  = e0 + cnt;

  const uint32_t colb = (uint32_t)((jg << 8) + (lane << 2));  // byte off in row
  const char* __restrict__ wb = (const char*)W1T;

  // starting bin: largest k with bst[k] <= e0
  int k = 0;
  while (bst[k + 1] <= (uint32_t)e0) ++k;

  float SA = 0.f, SC = 0.f;
  int n = e0;
  while (n < e1) {
    const int kend = min((int)bst[k + 1], e1);
#pragma unroll 4
    for (; n < kend; ++n) {
      uint2 r = recs[n];                            // broadcast ds_read_b64
      float w = *(const float*)(wb + (size_t)(r.x + colb));  // coalesced
      SA += w;
      SC = fmaf(w, __uint_as_float(r.y), SC);
    }
    atomicAdd(&bins[0][k][lane], __float2int_rn(SA * SCL_));  // rare flush
    atomicAdd(&bins[1][k][lane], __float2int_rn(SC * SCL_));
    SA = 0.f; SC = 0.f;
    ++k;
  }
  __syncthreads();

  // phase 2: tid < 64, thread owns j = jg*64 + tid (r19 verbatim)
  if (tid < 64) {
    float sa = 0.f, sc = 0.f;
    int cnd = NT_;
#pragma unroll 1
    for (int tt = 0; tt < NT_; ++tt) {
      if (tt < NB1_) {
        sa += (float)bins[0][tt][tid] * ISCL_;
        sc += (float)bins[1][tt][tid] * ISCL_;
      }
      float mv = (float)tt * DT_ * sa - sc;
      if (cnd == NT_ && mv >= 1.0f) cnd = tt;
    }
    cnd = min(cnd, NT_ - 1);                   // forced spike at last step
    idx1[((size_t)b << 10) + (jg << 6) + tid] = (uint8_t)cnd;
  }
}

// ---------------------------------------------------------------------------
// Layer-2 (r20/r21's no-LDS version): block = (b,j), 4 waves split i-range;
// lane = t.  W2[j][i] and idx1[b][i] wave-uniform -> uniform loads, zero DS.
// ---------------------------------------------------------------------------
__global__ __launch_bounds__(256) void k_main2(const uint8_t* __restrict__ idx1,
                                               const float* __restrict__ W2,
                                               float* __restrict__ out) {
  __shared__ float part[4][3][64];
  const int blk = blockIdx.x;          // 640
  const int b   = blk / 10;
  const int j   = blk - b * 10;
  const int tid = threadIdx.x;
  const int lane = tid & 63, wvv = tid >> 6;

  const float4*   __restrict__ w4 = (const float4*)(W2 + (size_t)j * F1_);
  const uint32_t* __restrict__ h4 = (const uint32_t*)(idx1 + ((size_t)b << 10));

  const float tl0 = (float)lane * DT_;
  const float tl1 = (float)(lane + 64) * DT_;
  const float tl2 = (float)(lane + 128) * DT_;
  float m0 = 0.f, m1 = 0.f, m2 = 0.f;
  const int q0 = wvv * 64;
#pragma unroll 4
  for (int q = q0; q < q0 + 64; ++q) {          // 4 i's per iter
    float4   w  = w4[q];                        // uniform
    uint32_t hh = h4[q];                        // uniform
#define E2(we_, sh_) {                                                        \
      float tiv = (float)((hh >> (sh_)) & 255u) * DT_;                        \
      m0 = fmaf((we_), fmaxf(tl0 - tiv, 0.f), m0);                            \
      m1 = fmaf((we_), fmaxf(tl1 - tiv, 0.f), m1);                            \
      m2 = fmaf((we_), fmaxf(tl2 - tiv, 0.f), m2); }
    E2(w.x, 0); E2(w.y, 8); E2(w.z, 16); E2(w.w, 24);
#undef E2
  }
  part[wvv][0][lane] = m0;
  part[wvv][1][lane] = m1;
  part[wvv][2][lane] = m2;
  __syncthreads();

  if (wvv == 0) {
    m0 = part[0][0][lane] + part[1][0][lane] + part[2][0][lane] + part[3][0][lane];
    m1 = part[0][1][lane] + part[1][1][lane] + part[2][1][lane] + part[3][1][lane];
    m2 = part[0][2][lane] + part[1][2][lane] + part[2][2][lane] + part[3][2][lane];
    unsigned long long b0 = __ballot(m0 >= 1.0f);
    unsigned long long b1 = __ballot(m1 >= 1.0f);
    unsigned long long b2 = __ballot(m2 >= 1.0f);
    b2 &= (1ull << 23) - 1;            // t <= 150
    b2 |= (1ull << 22);                // forced spike at t = 150
    int tres;
    if (b0)      tres = __ffsll((long long)b0) - 1;
    else if (b1) tres = 64 + __ffsll((long long)b1) - 1;
    else         tres = 128 + __ffsll((long long)b2) - 1;
    if (lane == 0) out[(size_t)b * F2_ + j] = (float)tres * DT_;
  }
}

}  // namespace

// ---------------------------------------------------------------------------
extern "C" void kernel_launch(void* const* d_in, const int* in_sizes, int n_in,
                              void* d_out, int out_size, void* d_ws, size_t ws_size,
                              hipStream_t stream) {
  const float* ti = (const float*)d_in[0];   // [64][1876]
  const float* W1 = (const float*)d_in[1];   // [1024][1876]
  const float* W2 = (const float*)d_in[2];   // [10][1024]
  float* out = (float*)d_out;                // [64][10]

  char* ws = (char*)d_ws;
  float*    W1T  = (float*)(ws + OFF_W1T);
  uint2*    sPr  = (uint2*)(ws + OFF_PAIR);
  uint32_t* bstG = (uint32_t*)(ws + OFF_BST);
  uint8_t*  idx1 = (uint8_t*)(ws + OFF_IDX1);

  hipLaunchKernelGGL(k_prep,  dim3(NBLK_T + B_), dim3(256), 0, stream,
                     W1, ti, W1T, sPr, bstG);
  hipLaunchKernelGGL(k_main1, dim3(1024), dim3(512), 0, stream,
                     sPr, bstG, W1T, idx1);
  hipLaunchKernelGGL(k_main2, dim3(640),  dim3(256), 0, stream, idx1, W2, out);
}